// Round 14
// baseline (312.494 us; speedup 1.0000x reference)
//
#include <hip/hip_runtime.h>

#define NEDGES 1600000
#define NNODES 100000
#define NF 128
#define NBUCK 391              // ceil(100000/256): buckets of 256 nodes
#define NBLKA 391              // ceil(1600000/4096): phase-A blocks, 4096 edges
#define NOFF  (NBUCK * NBLKA)  // 152881 (bucket-major count matrix)
#define NSB   150              // ceil(NOFF/1024) scan blocks

typedef short s16x8 __attribute__((ext_vector_type(8)));
typedef float f32x4 __attribute__((ext_vector_type(4)));

// ---- workspace byte layout (16B aligned blocks) ----
#define BH_B     0u          // int[152881] per-(bucket,block) counts
#define BHO_B    611584u     // int[152881] exclusive scan of BH
#define SST_B    1223168u    // u64[160] lookback state
#define ROWPTR_B 1224448u    // int[100001]
#define BKT_B    1624512u    // u32[1600000] bucket-major (eid<<8|local)
#define EIDS_B   8024512u    // u32[1600000] CSR (eid<<4|node&15)
#define WBF_B    14424512u   // ushort[16384]

static __device__ __forceinline__ unsigned short f2bf(float x) {
    unsigned u = __float_as_uint(x);
    return (unsigned short)((u + 0x7fffu + ((u >> 16) & 1u)) >> 16);  // RNE
}

// ---------------------------------------------------------------------------
// Phase A1: per-block LDS histogram over 391 buckets (bucket = dst>>8).
// All per-edge RMW is ds_add (global atomic rate cap ~24G/s was R12's proven
// dead end). Also zeroes the lookback state (replaces the memset dispatch —
// safe: k_scanB is launched after this kernel completes) and folds W->bf16.
// ---------------------------------------------------------------------------
__global__ __launch_bounds__(256) void k_bhist(const int* __restrict__ dst,
                                               int* __restrict__ bh,
                                               const float* __restrict__ W,
                                               unsigned short* __restrict__ Wb,
                                               unsigned long long* __restrict__ sstate) {
    __shared__ int cnt[NBUCK];
    const int t = threadIdx.x, b = blockIdx.x;
    const int g = b * 256 + t;
    if (g < NF * NF) Wb[g] = f2bf(W[g]);
    if (b == 0 && t < 160) sstate[t] = 0ull;
    for (int k = t; k < NBUCK; k += 256) cnt[k] = 0;
    __syncthreads();
    const int base = b * 4096;
    #pragma unroll
    for (int j = 0; j < 4; ++j) {
        const int i = base + j * 1024 + t * 4;
        if (i + 4 <= NEDGES) {
            const int4 d = *(const int4*)(dst + i);
            atomicAdd(&cnt[d.x >> 8], 1);
            atomicAdd(&cnt[d.y >> 8], 1);
            atomicAdd(&cnt[d.z >> 8], 1);
            atomicAdd(&cnt[d.w >> 8], 1);
        } else {
            for (int e = i; e < NEDGES; ++e) atomicAdd(&cnt[dst[e] >> 8], 1);
        }
    }
    __syncthreads();
    for (int k = t; k < NBUCK; k += 256) bh[k * NBLKA + b] = cnt[k];
}

// ---------------------------------------------------------------------------
// Generic exclusive scan over NOFF ints, wave-parallel decoupled lookback
// (R11-verified, incl. the m2==0 consume-whole-window fix).
// 150 blocks co-resident => spin cannot deadlock.
// ---------------------------------------------------------------------------
__global__ __launch_bounds__(256) void k_scanB(const int* __restrict__ in,
                                               int* __restrict__ outp,
                                               unsigned long long* __restrict__ state) {
    const int t = threadIdx.x, b = blockIdx.x;
    const int lane = t & 63, wv = t >> 6;
    const int i0 = b * 1024 + t * 4;
    int v0 = 0, v1 = 0, v2 = 0, v3 = 0;
    if (i0 + 4 <= NOFF) {
        const int4 q = *(const int4*)(in + i0);
        v0 = q.x; v1 = q.y; v2 = q.z; v3 = q.w;
    } else if (i0 < NOFF) {
        v0 = in[i0];
        if (i0 + 1 < NOFF) v1 = in[i0 + 1];
        if (i0 + 2 < NOFF) v2 = in[i0 + 2];
    }
    const int tsum = v0 + v1 + v2 + v3;
    int winc = tsum;
    #pragma unroll
    for (int d = 1; d < 64; d <<= 1) {
        const int u = __shfl_up(winc, d, 64);
        if (lane >= d) winc += u;
    }
    __shared__ int wsum[4];
    __shared__ int xbase;
    if (lane == 63) wsum[wv] = winc;
    __syncthreads();
    int woff = 0;
    #pragma unroll
    for (int w = 0; w < 3; ++w)
        if (wv > w) woff += wsum[w];
    const int tot = wsum[0] + wsum[1] + wsum[2] + wsum[3];

    if (wv == 0) {
        if (b > 0) {
            if (lane == 0)
                __hip_atomic_store(&state[b],
                                   ((unsigned long long)1 << 32) | (unsigned)tot,
                                   __ATOMIC_RELEASE, __HIP_MEMORY_SCOPE_AGENT);
            int excl = 0;
            int p = b - 1;
            for (;;) {
                const int idx = p - lane;
                unsigned long long s;
                do {
                    s = (idx >= 0)
                        ? __hip_atomic_load(&state[idx], __ATOMIC_ACQUIRE,
                                            __HIP_MEMORY_SCOPE_AGENT)
                        : ((unsigned long long)2 << 32);
                    if (!(s >> 32)) __builtin_amdgcn_s_sleep(2);
                } while (__any(!(s >> 32)));
                const unsigned long long m2 = __ballot((s >> 32) == 2);
                const int f = m2 ? (__ffsll((long long)m2) - 1) : 63;
                int c = (lane <= f) ? (int)(unsigned)s : 0;
                #pragma unroll
                for (int d = 32; d > 0; d >>= 1) c += __shfl_xor(c, d, 64);
                excl += c;
                if (m2) break;
                p -= 64;
            }
            if (lane == 0) {
                __hip_atomic_store(&state[b],
                                   ((unsigned long long)2 << 32) |
                                       (unsigned)(excl + tot),
                                   __ATOMIC_RELEASE, __HIP_MEMORY_SCOPE_AGENT);
                xbase = excl;
            }
        } else {
            if (lane == 0) {
                __hip_atomic_store(&state[0],
                                   ((unsigned long long)2 << 32) | (unsigned)tot,
                                   __ATOMIC_RELEASE, __HIP_MEMORY_SCOPE_AGENT);
                xbase = 0;
            }
        }
    }
    __syncthreads();

    const int base = xbase + woff + (winc - tsum);
    if (i0 + 4 <= NOFF) {
        int4 r;
        r.x = base; r.y = base + v0; r.z = base + v0 + v1; r.w = base + v0 + v1 + v2;
        *(int4*)(outp + i0) = r;
    } else if (i0 < NOFF) {
        outp[i0] = base;
        if (i0 + 1 < NOFF) outp[i0 + 1] = base + v0;
        if (i0 + 2 < NOFF) outp[i0 + 2] = base + v0 + v1;
    }
}

// ---------------------------------------------------------------------------
// Phase A2: scatter edges bucket-major (LDS cursor rank, nontemporal stores).
// ---------------------------------------------------------------------------
__global__ __launch_bounds__(256) void k_scatterA(const int* __restrict__ dst,
                                                  const int* __restrict__ bhoff,
                                                  unsigned* __restrict__ bucketed) {
    __shared__ int cur[NBUCK];
    const int t = threadIdx.x, b = blockIdx.x;
    for (int k = t; k < NBUCK; k += 256) cur[k] = 0;
    __syncthreads();
    const int base = b * 4096;
    #pragma unroll
    for (int j = 0; j < 4; ++j) {
        const int i = base + j * 1024 + t * 4;
        if (i + 4 <= NEDGES) {
            const int4 d = *(const int4*)(dst + i);
            const int r0 = atomicAdd(&cur[d.x >> 8], 1);
            const int r1 = atomicAdd(&cur[d.y >> 8], 1);
            const int r2 = atomicAdd(&cur[d.z >> 8], 1);
            const int r3 = atomicAdd(&cur[d.w >> 8], 1);
            __builtin_nontemporal_store(((unsigned)(i + 0) << 8) | (unsigned)(d.x & 255),
                                        bucketed + bhoff[(d.x >> 8) * NBLKA + b] + r0);
            __builtin_nontemporal_store(((unsigned)(i + 1) << 8) | (unsigned)(d.y & 255),
                                        bucketed + bhoff[(d.y >> 8) * NBLKA + b] + r1);
            __builtin_nontemporal_store(((unsigned)(i + 2) << 8) | (unsigned)(d.z & 255),
                                        bucketed + bhoff[(d.z >> 8) * NBLKA + b] + r2);
            __builtin_nontemporal_store(((unsigned)(i + 3) << 8) | (unsigned)(d.w & 255),
                                        bucketed + bhoff[(d.w >> 8) * NBLKA + b] + r3);
        } else {
            for (int e = i; e < NEDGES; ++e) {
                const int d = dst[e];
                const int r = atomicAdd(&cur[d >> 8], 1);
                bucketed[bhoff[(d >> 8) * NBLKA + b] + r] =
                    ((unsigned)e << 8) | (unsigned)(d & 255);
            }
        }
    }
}

// ---------------------------------------------------------------------------
// Phase B: one block per bucket (256 nodes). LDS hist -> LDS scan -> rowptr
// slice + node-sorted CSR eids (nontemporal stores, contiguous region).
// ---------------------------------------------------------------------------
__global__ __launch_bounds__(256) void k_bucket(const unsigned* __restrict__ bucketed,
                                                const int* __restrict__ bhoff,
                                                int* __restrict__ rowptr,
                                                unsigned* __restrict__ eids) {
    __shared__ int cnt[256], rnk[256], exc[256];
    __shared__ int wtot[4];
    const int t = threadIdx.x, k = blockIdx.x;
    const int lane = t & 63, wv = t >> 6;
    cnt[t] = 0;
    rnk[t] = 0;
    __syncthreads();
    const int ebase = bhoff[k * NBLKA];
    const int eend  = (k + 1 < NBUCK) ? bhoff[(k + 1) * NBLKA] : NEDGES;
    const int ecnt  = eend - ebase;

    for (int i = t; i < ecnt; i += 256)
        atomicAdd(&cnt[bucketed[ebase + i] & 255u], 1);
    __syncthreads();

    const int own = cnt[t];
    int incl = own;
    #pragma unroll
    for (int d = 1; d < 64; d <<= 1) {
        const int u = __shfl_up(incl, d, 64);
        if (lane >= d) incl += u;
    }
    if (lane == 63) wtot[wv] = incl;
    __syncthreads();
    int woff = 0;
    #pragma unroll
    for (int w = 0; w < 3; ++w)
        if (wv > w) woff += wtot[w];
    exc[t] = woff + incl - own;
    __syncthreads();

    const int node = k * 256 + t;
    if (node < NNODES) rowptr[node] = ebase + exc[t];
    if (k == 0 && t == 0) rowptr[NNODES] = NEDGES;

    for (int i = t; i < ecnt; i += 256) {
        const unsigned u = bucketed[ebase + i];
        const int local = (int)(u & 255u);
        const int r = atomicAdd(&rnk[local], 1);
        __builtin_nontemporal_store(((u >> 8) << 4) | (unsigned)(local & 15),
                                    eids + ebase + exc[local] + r);
    }
}

// ---------------------------------------------------------------------------
// Fused gather + mean + (W @ agg + b) + ReLU — R6/R11-verified gather core.
// R14 deltas: (1) nontemporal edge-row loads (read-once 819MB stream, keep
// L2/L3 for metadata), (2) coalesced epilogue — MFMA results staged in aggf
// (dead after pack) and written as full 512B rows instead of 64B runs.
// Per-edge ds_add consumption of 512B loads is the proven-slow path (R3/R5)
// — do NOT reintroduce.
// ---------------------------------------------------------------------------
__global__ __launch_bounds__(256) void k_fused(
        const float* __restrict__ edge, const int* __restrict__ rowptr,
        const unsigned* __restrict__ eids, const unsigned short* __restrict__ Wb,
        const float* __restrict__ bias, float* __restrict__ out) {
    __shared__ float aggf[16][132];
    __shared__ __align__(16) char aggb[16 * 256];
    const int tid  = threadIdx.x;
    const int lane = tid & 63;
    const int wv   = tid >> 6;
    const int l15  = lane & 15;
    const int l4   = lane >> 4;
    const int n0   = blockIdx.x * 16;

    for (int idx = tid; idx < 16 * 132; idx += 256)
        (&aggf[0][0])[idx] = 0.0f;
    __syncthreads();

    const int eb    = rowptr[n0];
    const int ee    = rowptr[n0 + 16];
    const int chunk = (ee - eb + 3) >> 2;
    const int wcs   = eb + wv * chunk;
    const int wce   = min(wcs + chunk, ee);

    int   cur = -1;
    float a0 = 0.f, a1 = 0.f;

    for (int base = wcs; base < wce; base += 64) {
        const int m = min(64, wce - base);
        const unsigned ev = (lane < m) ? eids[base + lane] : 0u;
        int b = 0;
        for (; b + 16 <= m; b += 16) {
            unsigned id[16];
            int      rw[16];
            #pragma unroll
            for (int j = 0; j < 16; ++j) {
                const unsigned u = (unsigned)__builtin_amdgcn_readlane((int)ev, b + j);
                id[j] = u >> 4;
                rw[j] = (int)(u & 15u);
            }
            float2 xv[16];
            #pragma unroll
            for (int j = 0; j < 16; ++j) {
                const double dv = __builtin_nontemporal_load(
                    (const double*)(edge + (size_t)id[j] * NF + lane * 2));
                __builtin_memcpy(&xv[j], &dv, 8);
            }
            #pragma unroll
            for (int j = 0; j < 16; ++j) {
                if (rw[j] != cur) {            // wave-uniform scalar branch
                    if (cur >= 0) {
                        atomicAdd(&aggf[cur][lane], a0);
                        atomicAdd(&aggf[cur][64 + lane], a1);
                    }
                    cur = rw[j];
                    a0 = 0.f; a1 = 0.f;
                }
                a0 += xv[j].x;
                a1 += xv[j].y;
            }
        }
        for (; b < m; ++b) {
            const unsigned u = (unsigned)__builtin_amdgcn_readlane((int)ev, b);
            const float2 v = *(const float2*)(edge + (size_t)(u >> 4) * NF + lane * 2);
            const int r = (int)(u & 15u);
            if (r != cur) {
                if (cur >= 0) {
                    atomicAdd(&aggf[cur][lane], a0);
                    atomicAdd(&aggf[cur][64 + lane], a1);
                }
                cur = r;
                a0 = 0.f; a1 = 0.f;
            }
            a0 += v.x;
            a1 += v.y;
        }
    }
    if (cur >= 0) {
        atomicAdd(&aggf[cur][lane], a0);
        atomicAdd(&aggf[cur][64 + lane], a1);
    }
    __syncthreads();

    // mean + bf16 pack into XOR-swizzled tile.
    {
        const int r  = tid >> 4;
        const int p0 = (tid & 15) * 4;
        const int cs = rowptr[n0 + r];
        const int ce = rowptr[n0 + r + 1];
        const float inv = 1.0f / fmaxf((float)(ce - cs), 1.0f);
        const float4 xv = *(const float4*)&aggf[r][p0];
        const float4 yv = *(const float4*)&aggf[r][64 + p0];
        const float xa[4] = {xv.x, xv.y, xv.z, xv.w};
        const float ya[4] = {yv.x, yv.y, yv.z, yv.w};
        #pragma unroll
        for (int j = 0; j < 4; ++j) {
            const unsigned pk = (unsigned)f2bf(xa[j] * inv) |
                                ((unsigned)f2bf(ya[j] * inv) << 16);
            const int byt = ((r * 256 + (p0 + j) * 4) ^ ((r & 7) << 4));
            *(unsigned*)(aggb + byt) = pk;
        }
    }
    __syncthreads();

    // MFMA. B[k][n] = W[j0+n][k]; D: col=lane&15, row=(lane>>4)*4+reg (m89).
    // Results (bias+relu applied) staged into aggf for coalesced row stores.
    #pragma unroll
    for (int t = 0; t < 2; ++t) {
        const int j0 = (wv * 2 + t) * 16;
        f32x4 acc = {0.f, 0.f, 0.f, 0.f};
        #pragma unroll
        for (int ks = 0; ks < 4; ++ks) {
            const s16x8 wfv = *(const s16x8*)((const char*)Wb +
                                              (j0 + l15) * 256 + ks * 64 + l4 * 16);
            const int byt = ((l15 * 256 + ks * 64 + l4 * 16) ^ ((l15 & 7) << 4));
            const s16x8 av = *(const s16x8*)(aggb + byt);
            acc = __builtin_amdgcn_mfma_f32_16x16x32_bf16(av, wfv, acc, 0, 0, 0);
        }
        const float bj = bias[j0 + l15];
        #pragma unroll
        for (int r = 0; r < 4; ++r) {
            const int m = l4 * 4 + r;
            aggf[m][j0 + l15] = fmaxf(acc[r] + bj, 0.f);
        }
    }
    __syncthreads();

    // Coalesced epilogue: thread t writes row t>>4, 8 consecutive floats —
    // each 16-thread group emits one full 512B row.
    {
        const int r  = tid >> 4;
        const int c0 = (tid & 15) * 8;
        float4 v0 = *(const float4*)&aggf[r][c0];
        float4 v1 = *(const float4*)&aggf[r][c0 + 4];
        float* dst = out + (size_t)(n0 + r) * NF + c0;
        *(float4*)dst       = v0;
        *(float4*)(dst + 4) = v1;
    }
}

extern "C" void kernel_launch(void* const* d_in, const int* in_sizes, int n_in,
                              void* d_out, int out_size, void* d_ws, size_t ws_size,
                              hipStream_t stream) {
    const float* edge = (const float*)d_in[0];
    const int*   dst  = (const int*)d_in[1];
    const float* W    = (const float*)d_in[2];
    const float* b    = (const float*)d_in[3];
    float* out = (float*)d_out;

    char* ws = (char*)d_ws;
    int*                bh       = (int*)(ws + BH_B);
    int*                bhoff    = (int*)(ws + BHO_B);
    unsigned long long* sstate   = (unsigned long long*)(ws + SST_B);
    int*                rowptr   = (int*)(ws + ROWPTR_B);
    unsigned*           bucketed = (unsigned*)(ws + BKT_B);
    unsigned*           eids     = (unsigned*)(ws + EIDS_B);
    unsigned short*     Wb       = (unsigned short*)(ws + WBF_B);

    k_bhist<<<NBLKA, 256, 0, stream>>>(dst, bh, W, Wb, sstate);
    k_scanB<<<NSB, 256, 0, stream>>>(bh, bhoff, sstate);
    k_scatterA<<<NBLKA, 256, 0, stream>>>(dst, bhoff, bucketed);
    k_bucket<<<NBUCK, 256, 0, stream>>>(bucketed, bhoff, rowptr, eids);
    k_fused<<<NNODES / 16, 256, 0, stream>>>(edge, rowptr, eids, Wb, b, out);
}

// Round 15
// 234.395 us; speedup vs baseline: 1.3332x; 1.3332x over previous
//
#include <hip/hip_runtime.h>

#define NEDGES 1600000
#define NNODES 100000
#define NF 128
#define NBUCK 391              // ceil(100000/256): buckets of 256 nodes
#define NBLKA 391              // ceil(1600000/4096): phase-A blocks, 4096 edges
#define NOFF  (NBUCK * NBLKA)  // 152881 (bucket-major count matrix)
#define NSB   150              // ceil(NOFF/1024) scan blocks

typedef short s16x8 __attribute__((ext_vector_type(8)));
typedef float f32x4 __attribute__((ext_vector_type(4)));

// ---- workspace byte layout (16B aligned blocks) ----
#define BH_B     0u          // int[152881] per-(bucket,block) counts
#define BHO_B    611584u     // int[152881] exclusive scan of BH
#define SST_B    1223168u    // u64[160] lookback state
#define ROWPTR_B 1224448u    // int[100001]
#define BKT_B    1624512u    // u32[1600000] bucket-major (eid<<8|local)
#define EIDS_B   8024512u    // u32[1600000] CSR (eid<<4|node&15)
#define WBF_B    14424512u   // ushort[16384]

static __device__ __forceinline__ unsigned short f2bf(float x) {
    unsigned u = __float_as_uint(x);
    return (unsigned short)((u + 0x7fffu + ((u >> 16) & 1u)) >> 16);  // RNE
}

// ---------------------------------------------------------------------------
// Phase A1: per-block LDS histogram over 391 buckets (bucket = dst>>8).
// All per-edge RMW is ds_add (global atomic rate cap ~24G/s, R12 dead end).
// Zeroes lookback state (k_scanB runs strictly after) and folds W->bf16.
// NOTE R14 lesson: NO nontemporal hints anywhere — NT edge loads + NT
// metadata stores cost +72us (240->312). Plain loads/stores only.
// ---------------------------------------------------------------------------
__global__ __launch_bounds__(256) void k_bhist(const int* __restrict__ dst,
                                               int* __restrict__ bh,
                                               const float* __restrict__ W,
                                               unsigned short* __restrict__ Wb,
                                               unsigned long long* __restrict__ sstate) {
    __shared__ int cnt[NBUCK];
    const int t = threadIdx.x, b = blockIdx.x;
    const int g = b * 256 + t;
    if (g < NF * NF) Wb[g] = f2bf(W[g]);
    if (b == 0 && t < 160) sstate[t] = 0ull;
    for (int k = t; k < NBUCK; k += 256) cnt[k] = 0;
    __syncthreads();
    const int base = b * 4096;
    #pragma unroll
    for (int j = 0; j < 4; ++j) {
        const int i = base + j * 1024 + t * 4;
        if (i + 4 <= NEDGES) {
            const int4 d = *(const int4*)(dst + i);
            atomicAdd(&cnt[d.x >> 8], 1);
            atomicAdd(&cnt[d.y >> 8], 1);
            atomicAdd(&cnt[d.z >> 8], 1);
            atomicAdd(&cnt[d.w >> 8], 1);
        } else {
            for (int e = i; e < NEDGES; ++e) atomicAdd(&cnt[dst[e] >> 8], 1);
        }
    }
    __syncthreads();
    for (int k = t; k < NBUCK; k += 256) bh[k * NBLKA + b] = cnt[k];
}

// ---------------------------------------------------------------------------
// Generic exclusive scan over NOFF ints, wave-parallel decoupled lookback
// (R11-verified, incl. the m2==0 consume-whole-window fix).
// 150 blocks co-resident => spin cannot deadlock.
// ---------------------------------------------------------------------------
__global__ __launch_bounds__(256) void k_scanB(const int* __restrict__ in,
                                               int* __restrict__ outp,
                                               unsigned long long* __restrict__ state) {
    const int t = threadIdx.x, b = blockIdx.x;
    const int lane = t & 63, wv = t >> 6;
    const int i0 = b * 1024 + t * 4;
    int v0 = 0, v1 = 0, v2 = 0, v3 = 0;
    if (i0 + 4 <= NOFF) {
        const int4 q = *(const int4*)(in + i0);
        v0 = q.x; v1 = q.y; v2 = q.z; v3 = q.w;
    } else if (i0 < NOFF) {
        v0 = in[i0];
        if (i0 + 1 < NOFF) v1 = in[i0 + 1];
        if (i0 + 2 < NOFF) v2 = in[i0 + 2];
    }
    const int tsum = v0 + v1 + v2 + v3;
    int winc = tsum;
    #pragma unroll
    for (int d = 1; d < 64; d <<= 1) {
        const int u = __shfl_up(winc, d, 64);
        if (lane >= d) winc += u;
    }
    __shared__ int wsum[4];
    __shared__ int xbase;
    if (lane == 63) wsum[wv] = winc;
    __syncthreads();
    int woff = 0;
    #pragma unroll
    for (int w = 0; w < 3; ++w)
        if (wv > w) woff += wsum[w];
    const int tot = wsum[0] + wsum[1] + wsum[2] + wsum[3];

    if (wv == 0) {
        if (b > 0) {
            if (lane == 0)
                __hip_atomic_store(&state[b],
                                   ((unsigned long long)1 << 32) | (unsigned)tot,
                                   __ATOMIC_RELEASE, __HIP_MEMORY_SCOPE_AGENT);
            int excl = 0;
            int p = b - 1;
            for (;;) {
                const int idx = p - lane;
                unsigned long long s;
                do {
                    s = (idx >= 0)
                        ? __hip_atomic_load(&state[idx], __ATOMIC_ACQUIRE,
                                            __HIP_MEMORY_SCOPE_AGENT)
                        : ((unsigned long long)2 << 32);
                    if (!(s >> 32)) __builtin_amdgcn_s_sleep(2);
                } while (__any(!(s >> 32)));
                const unsigned long long m2 = __ballot((s >> 32) == 2);
                const int f = m2 ? (__ffsll((long long)m2) - 1) : 63;
                int c = (lane <= f) ? (int)(unsigned)s : 0;
                #pragma unroll
                for (int d = 32; d > 0; d >>= 1) c += __shfl_xor(c, d, 64);
                excl += c;
                if (m2) break;
                p -= 64;
            }
            if (lane == 0) {
                __hip_atomic_store(&state[b],
                                   ((unsigned long long)2 << 32) |
                                       (unsigned)(excl + tot),
                                   __ATOMIC_RELEASE, __HIP_MEMORY_SCOPE_AGENT);
                xbase = excl;
            }
        } else {
            if (lane == 0) {
                __hip_atomic_store(&state[0],
                                   ((unsigned long long)2 << 32) | (unsigned)tot,
                                   __ATOMIC_RELEASE, __HIP_MEMORY_SCOPE_AGENT);
                xbase = 0;
            }
        }
    }
    __syncthreads();

    const int base = xbase + woff + (winc - tsum);
    if (i0 + 4 <= NOFF) {
        int4 r;
        r.x = base; r.y = base + v0; r.z = base + v0 + v1; r.w = base + v0 + v1 + v2;
        *(int4*)(outp + i0) = r;
    } else if (i0 < NOFF) {
        outp[i0] = base;
        if (i0 + 1 < NOFF) outp[i0 + 1] = base + v0;
        if (i0 + 2 < NOFF) outp[i0 + 2] = base + v0 + v1;
    }
}

// ---------------------------------------------------------------------------
// Phase A2: scatter edges bucket-major (LDS cursor rank, plain stores).
// ---------------------------------------------------------------------------
__global__ __launch_bounds__(256) void k_scatterA(const int* __restrict__ dst,
                                                  const int* __restrict__ bhoff,
                                                  unsigned* __restrict__ bucketed) {
    __shared__ int cur[NBUCK];
    const int t = threadIdx.x, b = blockIdx.x;
    for (int k = t; k < NBUCK; k += 256) cur[k] = 0;
    __syncthreads();
    const int base = b * 4096;
    #pragma unroll
    for (int j = 0; j < 4; ++j) {
        const int i = base + j * 1024 + t * 4;
        if (i + 4 <= NEDGES) {
            const int4 d = *(const int4*)(dst + i);
            const int r0 = atomicAdd(&cur[d.x >> 8], 1);
            const int r1 = atomicAdd(&cur[d.y >> 8], 1);
            const int r2 = atomicAdd(&cur[d.z >> 8], 1);
            const int r3 = atomicAdd(&cur[d.w >> 8], 1);
            bucketed[bhoff[(d.x >> 8) * NBLKA + b] + r0] =
                ((unsigned)(i + 0) << 8) | (unsigned)(d.x & 255);
            bucketed[bhoff[(d.y >> 8) * NBLKA + b] + r1] =
                ((unsigned)(i + 1) << 8) | (unsigned)(d.y & 255);
            bucketed[bhoff[(d.z >> 8) * NBLKA + b] + r2] =
                ((unsigned)(i + 2) << 8) | (unsigned)(d.z & 255);
            bucketed[bhoff[(d.w >> 8) * NBLKA + b] + r3] =
                ((unsigned)(i + 3) << 8) | (unsigned)(d.w & 255);
        } else {
            for (int e = i; e < NEDGES; ++e) {
                const int d = dst[e];
                const int r = atomicAdd(&cur[d >> 8], 1);
                bucketed[bhoff[(d >> 8) * NBLKA + b] + r] =
                    ((unsigned)e << 8) | (unsigned)(d & 255);
            }
        }
    }
}

// ---------------------------------------------------------------------------
// Phase B: one block per bucket (256 nodes). LDS hist -> LDS scan -> rowptr
// slice + node-sorted CSR eids (plain stores, contiguous region).
// ---------------------------------------------------------------------------
__global__ __launch_bounds__(256) void k_bucket(const unsigned* __restrict__ bucketed,
                                                const int* __restrict__ bhoff,
                                                int* __restrict__ rowptr,
                                                unsigned* __restrict__ eids) {
    __shared__ int cnt[256], rnk[256], exc[256];
    __shared__ int wtot[4];
    const int t = threadIdx.x, k = blockIdx.x;
    const int lane = t & 63, wv = t >> 6;
    cnt[t] = 0;
    rnk[t] = 0;
    __syncthreads();
    const int ebase = bhoff[k * NBLKA];
    const int eend  = (k + 1 < NBUCK) ? bhoff[(k + 1) * NBLKA] : NEDGES;
    const int ecnt  = eend - ebase;

    for (int i = t; i < ecnt; i += 256)
        atomicAdd(&cnt[bucketed[ebase + i] & 255u], 1);
    __syncthreads();

    const int own = cnt[t];
    int incl = own;
    #pragma unroll
    for (int d = 1; d < 64; d <<= 1) {
        const int u = __shfl_up(incl, d, 64);
        if (lane >= d) incl += u;
    }
    if (lane == 63) wtot[wv] = incl;
    __syncthreads();
    int woff = 0;
    #pragma unroll
    for (int w = 0; w < 3; ++w)
        if (wv > w) woff += wtot[w];
    exc[t] = woff + incl - own;
    __syncthreads();

    const int node = k * 256 + t;
    if (node < NNODES) rowptr[node] = ebase + exc[t];
    if (k == 0 && t == 0) rowptr[NNODES] = NEDGES;

    for (int i = t; i < ecnt; i += 256) {
        const unsigned u = bucketed[ebase + i];
        const int local = (int)(u & 255u);
        const int r = atomicAdd(&rnk[local], 1);
        eids[ebase + exc[local] + r] = ((u >> 8) << 4) | (unsigned)(local & 15);
    }
}

// ---------------------------------------------------------------------------
// Fused gather + mean + (W @ agg + b) + ReLU — R6/R13-verified structure.
// Per-wave contiguous chunks, coalesced eids lane-load + readlane broadcast
// (no pointer-chase), 16-deep unconditional PLAIN 512B load batches,
// segmented REGISTER accumulation, conflict-free LDS flush. Proven-slow
// paths: per-edge ds_add consumption (R3/R5), nontemporal hints (R14).
// ---------------------------------------------------------------------------
__global__ __launch_bounds__(256) void k_fused(
        const float* __restrict__ edge, const int* __restrict__ rowptr,
        const unsigned* __restrict__ eids, const unsigned short* __restrict__ Wb,
        const float* __restrict__ bias, float* __restrict__ out) {
    __shared__ float aggf[16][132];
    __shared__ __align__(16) char aggb[16 * 256];
    const int tid  = threadIdx.x;
    const int lane = tid & 63;
    const int wv   = tid >> 6;
    const int l15  = lane & 15;
    const int l4   = lane >> 4;
    const int n0   = blockIdx.x * 16;

    for (int idx = tid; idx < 16 * 132; idx += 256)
        (&aggf[0][0])[idx] = 0.0f;
    __syncthreads();

    const int eb    = rowptr[n0];
    const int ee    = rowptr[n0 + 16];
    const int chunk = (ee - eb + 3) >> 2;
    const int wcs   = eb + wv * chunk;
    const int wce   = min(wcs + chunk, ee);

    int   cur = -1;
    float a0 = 0.f, a1 = 0.f;

    for (int base = wcs; base < wce; base += 64) {
        const int m = min(64, wce - base);
        const unsigned ev = (lane < m) ? eids[base + lane] : 0u;
        int b = 0;
        for (; b + 16 <= m; b += 16) {
            unsigned id[16];
            int      rw[16];
            #pragma unroll
            for (int j = 0; j < 16; ++j) {
                const unsigned u = (unsigned)__builtin_amdgcn_readlane((int)ev, b + j);
                id[j] = u >> 4;
                rw[j] = (int)(u & 15u);
            }
            float2 xv[16];
            #pragma unroll
            for (int j = 0; j < 16; ++j)
                xv[j] = *(const float2*)(edge + (size_t)id[j] * NF + lane * 2);
            #pragma unroll
            for (int j = 0; j < 16; ++j) {
                if (rw[j] != cur) {            // wave-uniform scalar branch
                    if (cur >= 0) {
                        atomicAdd(&aggf[cur][lane], a0);
                        atomicAdd(&aggf[cur][64 + lane], a1);
                    }
                    cur = rw[j];
                    a0 = 0.f; a1 = 0.f;
                }
                a0 += xv[j].x;
                a1 += xv[j].y;
            }
        }
        for (; b < m; ++b) {
            const unsigned u = (unsigned)__builtin_amdgcn_readlane((int)ev, b);
            const float2 v = *(const float2*)(edge + (size_t)(u >> 4) * NF + lane * 2);
            const int r = (int)(u & 15u);
            if (r != cur) {
                if (cur >= 0) {
                    atomicAdd(&aggf[cur][lane], a0);
                    atomicAdd(&aggf[cur][64 + lane], a1);
                }
                cur = r;
                a0 = 0.f; a1 = 0.f;
            }
            a0 += v.x;
            a1 += v.y;
        }
    }
    if (cur >= 0) {
        atomicAdd(&aggf[cur][lane], a0);
        atomicAdd(&aggf[cur][64 + lane], a1);
    }
    __syncthreads();

    // mean + bf16 pack into XOR-swizzled tile.
    {
        const int r  = tid >> 4;
        const int p0 = (tid & 15) * 4;
        const int cs = rowptr[n0 + r];
        const int ce = rowptr[n0 + r + 1];
        const float inv = 1.0f / fmaxf((float)(ce - cs), 1.0f);
        const float4 xv = *(const float4*)&aggf[r][p0];
        const float4 yv = *(const float4*)&aggf[r][64 + p0];
        const float xa[4] = {xv.x, xv.y, xv.z, xv.w};
        const float ya[4] = {yv.x, yv.y, yv.z, yv.w};
        #pragma unroll
        for (int j = 0; j < 4; ++j) {
            const unsigned pk = (unsigned)f2bf(xa[j] * inv) |
                                ((unsigned)f2bf(ya[j] * inv) << 16);
            const int byt = ((r * 256 + (p0 + j) * 4) ^ ((r & 7) << 4));
            *(unsigned*)(aggb + byt) = pk;
        }
    }
    __syncthreads();

    // MFMA. B[k][n] = W[j0+n][k]; D: col=lane&15, row=(lane>>4)*4+reg (m89).
    #pragma unroll
    for (int t = 0; t < 2; ++t) {
        const int j0 = (wv * 2 + t) * 16;
        f32x4 acc = {0.f, 0.f, 0.f, 0.f};
        #pragma unroll
        for (int ks = 0; ks < 4; ++ks) {
            const s16x8 wfv = *(const s16x8*)((const char*)Wb +
                                              (j0 + l15) * 256 + ks * 64 + l4 * 16);
            const int byt = ((l15 * 256 + ks * 64 + l4 * 16) ^ ((l15 & 7) << 4));
            const s16x8 av = *(const s16x8*)(aggb + byt);
            acc = __builtin_amdgcn_mfma_f32_16x16x32_bf16(av, wfv, acc, 0, 0, 0);
        }
        const float bj = bias[j0 + l15];
        #pragma unroll
        for (int r = 0; r < 4; ++r) {
            const int m = l4 * 4 + r;
            out[(size_t)(n0 + m) * NF + j0 + l15] = fmaxf(acc[r] + bj, 0.f);
        }
    }
}

extern "C" void kernel_launch(void* const* d_in, const int* in_sizes, int n_in,
                              void* d_out, int out_size, void* d_ws, size_t ws_size,
                              hipStream_t stream) {
    const float* edge = (const float*)d_in[0];
    const int*   dst  = (const int*)d_in[1];
    const float* W    = (const float*)d_in[2];
    const float* b    = (const float*)d_in[3];
    float* out = (float*)d_out;

    char* ws = (char*)d_ws;
    int*                bh       = (int*)(ws + BH_B);
    int*                bhoff    = (int*)(ws + BHO_B);
    unsigned long long* sstate   = (unsigned long long*)(ws + SST_B);
    int*                rowptr   = (int*)(ws + ROWPTR_B);
    unsigned*           bucketed = (unsigned*)(ws + BKT_B);
    unsigned*           eids     = (unsigned*)(ws + EIDS_B);
    unsigned short*     Wb       = (unsigned short*)(ws + WBF_B);

    k_bhist<<<NBLKA, 256, 0, stream>>>(dst, bh, W, Wb, sstate);
    k_scanB<<<NSB, 256, 0, stream>>>(bh, bhoff, sstate);
    k_scatterA<<<NBLKA, 256, 0, stream>>>(dst, bhoff, bucketed);
    k_bucket<<<NBUCK, 256, 0, stream>>>(bucketed, bhoff, rowptr, eids);
    k_fused<<<NNODES / 16, 256, 0, stream>>>(edge, rowptr, eids, Wb, b, out);
}